// Round 13
// baseline (230.669 us; speedup 1.0000x reference)
//
#include <hip/hip_runtime.h>

// ---------- types ----------
typedef __attribute__((ext_vector_type(8))) _Float16 half8;
typedef __attribute__((ext_vector_type(2))) __fp16 half2r;   // cvt_pkrtz return type
typedef __attribute__((ext_vector_type(4))) float f32x4;

#define AS1 __attribute__((address_space(1)))
#define AS3 __attribute__((address_space(3)))

union H2U { half2r h; unsigned int u; };
union Frag { half8 v; unsigned long long d[2]; };

__device__ __forceinline__ unsigned int pk(float a, float b) {
    H2U x; x.h = __builtin_amdgcn_cvt_pkrtz(a, b); return x.u;
}

__device__ __forceinline__ void gload_lds16(const void* g, void* l) {
    __builtin_amdgcn_global_load_lds((const AS1 unsigned int*)g,
                                     (AS3 unsigned int*)l, 16, 0, 0);
}

// ---------- problem constants ----------
// M = B*T = 32768, D_STATE = 1088, D_MODEL = 1024, D_LATENT = 128
// a16 / W1 layout: panel-tile 16 KB blocks at ((p*17 + t) << 14); within:
//   byte = (r<<7) + ((((kh<<2)|u) ^ (r&7)) << 4) + pos8   (R8-verified,
//   oct-conflict-free wave64 b128 frag reads; one MFMA frag = one 16-B slot)
#define WS2_OFF 2228224        // = 1024 rows * 2176 B  (W1 total size)
#define WS2_SZ  524288         // 2048 rows * 256 B
#define W2_ROWB 256            // kv weights: 2-slab 128-B layout
#define A16_SZ  71303168ull    // 32768 * 2176

// pick the fused-add source for 64-f32 slab ks (0..16)
__device__ __forceinline__ void pick_w(int ks, const float* wsp, const float* whp,
                                       const float* whs, const float* wtg,
                                       const float*& wbase, int& wstr, int& wko) {
    if (ks < 8)       { wbase = wsp; wstr = 512; wko = ks * 64; }
    else if (ks < 12) { wbase = whp; wstr = 256; wko = ks * 64 - 512; }
    else if (ks < 16) { wbase = whs; wstr = 256; wko = ks * 64 - 768; }
    else              { wbase = wtg; wstr = 64;  wko = 0; }
}

// packed-frag address within a 16-KB panel-tile block
__device__ __forceinline__ size_t pf_addr(int r, int kt) {
    int kh = kt >> 5, k32 = kt & 31;
    int u = (k32 & 15) >> 2, pos8 = (k32 >> 4) << 3;
    return ((size_t)r << 7) + ((size_t)((((kh << 2) | u) ^ (r & 7)) << 4)) + pos8;
}

// ============ prologue (dispatch 1): Wk|Wv -> f16 only ============
__global__ __launch_bounds__(256) void prep_w(const float* __restrict__ Wk,
                                              const float* __restrict__ Wv,
                                              char* __restrict__ ws) {
    int j = blockIdx.x * 256 + threadIdx.x;      // 65536 units
    int r = j >> 5;                              // 0..2047
    int k = (j & 31) << 2;                       // 0..124
    const float* src = (r < 1024) ? (Wk + (size_t)r * 128 + k)
                                  : (Wv + (size_t)(r - 1024) * 128 + k);
    f32x4 w = *(const f32x4*)src;
    uint2 q; q.x = pk(w.x, w.y); q.y = pk(w.z, w.w);
    size_t off = WS2_OFF + (size_t)r * W2_ROWB + ((k >> 6) << 7)
               + (((k & 63) << 1) ^ ((r & 7) << 4));
    *(uint2*)(ws + off) = q;
}

// ---------- fuse_a body (R9-identical) ----------
__device__ __forceinline__
void fuse_body(int u, const float* __restrict__ S, const float* __restrict__ wsp,
               const float* __restrict__ whp, const float* __restrict__ whs,
               const float* __restrict__ wtg, char* __restrict__ a16) {
    int row = u / 272;
    int rem = u % 272;
    int ks = rem >> 4;
    int k4 = (rem & 15) << 2;

    const float* wbase; int wstr, wko;
    pick_w(ks, wsp, whp, whs, wtg, wbase, wstr, wko);

    f32x4 s4 = *(const f32x4*)(S + (size_t)row * 1088 + ks * 64 + k4);
    f32x4 w4 = *(const f32x4*)(wbase + (size_t)row * wstr + wko + k4);
    uint2 q; q.x = pk(s4.x + w4.x, s4.y + w4.y);
             q.y = pk(s4.z + w4.z, s4.w + w4.w);
    size_t off = ((size_t)((row >> 7) * 17 + ks) << 14) + pf_addr(row & 127, k4);
    *(uint2*)(a16 + off) = q;
}

// ---------- kv body (R9-identical) ----------
__device__ __forceinline__
void kv_body(int mblk, int nb, const float* __restrict__ lat,
             const char* __restrict__ ws2, float* __restrict__ outk,
             float* __restrict__ outv, char* lds) {
    char* Al = lds;
    char* Bl = lds + 16384;

    int m0 = mblk << 7;
    int nrow0 = nb << 7;
    float* out = (nb < 8) ? outk : outv;
    int n0 = (nb & 7) << 7;

    int tid = threadIdx.x;
    int lane = tid & 63, wid = tid >> 6;
    int wm = (wid >> 1) << 6, wn = (wid & 1) << 6;
    int lp = lane & 15, lg = lane >> 4;

    f32x4 acc[4][4] = {};

    for (int ks = 0; ks < 2; ++ks) {
        __syncthreads();
        {
            const char* wrow = ws2 + (size_t)nrow0 * W2_ROWB + ks * 128;
            #pragma unroll
            for (int c = 0; c < 4; ++c) {
                int s = c * 4096 + wid * 1024 + lane * 16;
                int n = s >> 7, cb = s & 127;
                gload_lds16(wrow + (size_t)n * W2_ROWB + cb,
                            Bl + c * 4096 + wid * 1024);
            }
        }
        #pragma unroll
        for (int i = 0; i < 8; ++i) {
            int u = i * 256 + tid;
            int row = u >> 4;
            int k4 = (u & 15) << 2;
            f32x4 s4 = *(const f32x4*)(lat + (size_t)(m0 + row) * 128 + ks * 64 + k4);
            uint2 q; q.x = pk(s4.x, s4.y); q.y = pk(s4.z, s4.w);
            *(uint2*)(Al + (row << 7) + ((k4 << 1) ^ ((row & 7) << 4))) = q;
        }
        __syncthreads();

        #pragma unroll
        for (int b = 0; b < 2; ++b) {
            Frag af[4], bf[4];
            #pragma unroll
            for (int f = 0; f < 4; ++f) {
                int ra = wm + f * 16 + lp;  int xa = (ra & 7) << 4;
                af[f].d[0] = *(const unsigned long long*)(Al + (ra << 7) + ((b * 64 + lg * 8) ^ xa));
                af[f].d[1] = *(const unsigned long long*)(Al + (ra << 7) + ((b * 64 + 32 + lg * 8) ^ xa));
                int rb = wn + f * 16 + lp;  int xb = (rb & 7) << 4;
                bf[f].d[0] = *(const unsigned long long*)(Bl + (rb << 7) + ((b * 64 + lg * 8) ^ xb));
                bf[f].d[1] = *(const unsigned long long*)(Bl + (rb << 7) + ((b * 64 + 32 + lg * 8) ^ xb));
            }
            #pragma unroll
            for (int i = 0; i < 4; ++i)
                #pragma unroll
                for (int j = 0; j < 4; ++j)
                    acc[i][j] = __builtin_amdgcn_mfma_f32_16x16x32_f16(af[i].v, bf[j].v, acc[i][j], 0, 0, 0);
        }
    }

    #pragma unroll
    for (int i = 0; i < 4; ++i)
        #pragma unroll
        for (int j = 0; j < 4; ++j) {
            int row = m0 + wm + i * 16 + (lg << 2);
            int col = n0 + wn + j * 16 + lp;
            float* p = out + (size_t)row * 1024 + col;
            #pragma unroll
            for (int r = 0; r < 4; ++r) p[(size_t)r * 1024] = acc[i][j][r];
        }
}

// ============ merged fuse_a || gemm_kv || W1-prep (R12-identical) ============
__global__ __launch_bounds__(256, 3)
void fuse_kv(const float* __restrict__ S, const float* __restrict__ wsp,
             const float* __restrict__ whp, const float* __restrict__ whs,
             const float* __restrict__ wtg, char* __restrict__ a16,
             const float* __restrict__ lat, const char* __restrict__ ws2,
             float* __restrict__ outk, float* __restrict__ outv,
             const float* __restrict__ Wr, char* __restrict__ ws,
             int kvpg, int gsz, int nmain) {
    __shared__ char lds[32768];
    int bid = blockIdx.x;
    if (bid >= nmain) {                          // ---- W1-prep tail role
        int id = (bid - nmain) * 256 + threadIdx.x;
        int n = id / 272;
        int k = (id % 272) * 4;
        f32x4 w = *(const f32x4*)(Wr + (size_t)n * 1088 + k);
        uint2 q; q.x = pk(w.x, w.y); q.y = pk(w.z, w.w);
        int t = k >> 6;
        size_t off = ((size_t)((n >> 7) * 17 + t) << 14) + pf_addr(n & 127, k & 63);
        *(uint2*)(ws + off) = q;
        return;
    }
    int g = bid / gsz, slot = bid - g * gsz;
    if (slot < 17) {
        fuse_body((g * 17 + slot) * 256 + threadIdx.x, S, wsp, whp, whs, wtg, a16);
    } else {
        int idx = g * kvpg + (slot - 17);
        int mblk, nb;
        if (kvpg == 2) { int wg = (idx & 7) * 512 + (idx >> 3); mblk = wg >> 4; nb = wg & 15; }
        else           { int wg = (idx & 7) * 256 + (idx >> 3); mblk = wg >> 3; nb = wg & 7; }
        kv_body(mblk, nb, lat, ws2, outk, outv, lds);
    }
}

// v-half standalone (fallback path)
__global__ __launch_bounds__(256, 3)
void gemm_v(const float* __restrict__ lat, const char* __restrict__ ws2,
            float* __restrict__ outk, float* __restrict__ outv) {
    __shared__ char lds[32768];
    int idx = blockIdx.x;
    int wg = (idx & 7) * 256 + (idx >> 3);
    kv_body(wg >> 3, 8 + (wg & 7), lat, ws2, outk, outv, lds);
}

// ============ GEMM1: out = Af16 @ W_read^T — 4-phase, early-paired staging ====
// BM=BN=256, BK=64, 8 waves (2M x 4N), wave tile 128x64, 2 x 64 KB LDS dbuf.
// CHANGE vs R9/R12: tile t+1's half-tiles stage in PAIRS at phases 0 and 1
// (was one per phase 0..3). Every half now has >=3 phases (~2000 cyc) of
// HBM-latency cover before tile t+1's vmcnt — R9 staged half3 at phase 3,
// giving its wait only ~1 phase of cover (exposed stall each tile).
// vmcnt(4) ONCE per tile at phase 0 (counted: t+1's first 4 loads fly on).
__global__ __launch_bounds__(512, 2)
void gemm_read(const char* __restrict__ a16, const char* __restrict__ wws,
               float* __restrict__ out) {
    extern __shared__ char lds[];                // 131072 B

    int bid = blockIdx.x;
    int wg   = (bid & 7) * 64 + (bid >> 3);      // bijective XCD swizzle (512%8==0)
    int mblk = wg >> 2, nblk = wg & 3;
    int m0 = mblk << 8, n0 = nblk << 8;

    int tid = threadIdx.x;
    int lane = tid & 63, wid = tid >> 6;
    int wm = (wid >> 2) << 7, wn = (wid & 3) << 6;   // wave tile: 128x64
    int lp = lane & 15, lg = lane >> 4;

    int aoff = (wid >> 2) * 16384;               // wave's A-half region
    int boff = 32768 + (wn >> 7) * 16384;        // wave's B-half region
    int cb64 = wn & 64;                          // col base within B-half

    const char* srcH[4];
    srcH[0] = a16 + ((size_t)((m0 >> 7) * 17) << 14);
    srcH[1] = srcH[0] + (17 << 14);
    srcH[2] = wws + ((size_t)((n0 >> 7) * 17) << 14);
    srcH[3] = srcH[2] + (17 << 14);

    f32x4 acc[8][4] = {};
    Frag af[4], bf[4];

#define STAGE(T, H, DB) do {                                               \
        const char* s_ = srcH[H] + ((size_t)(T) << 14);                    \
        char* d_ = lds + (DB) + (H) * 16384;                               \
        gload_lds16(s_ + tid * 16, d_ + tid * 16);                         \
        gload_lds16(s_ + 8192 + tid * 16, d_ + 8192 + tid * 16);           \
    } while (0)

#define LOADA(MH, KH, BB) do {                                             \
        _Pragma("unroll")                                                  \
        for (int f = 0; f < 4; ++f) {                                      \
            int r_ = (MH) * 64 + f * 16 + lp;                              \
            af[f] = *(const Frag*)(lds + (BB) + aoff + (r_ << 7)           \
                     + ((((((KH) << 2) | lg) ^ (r_ & 7))) << 4));          \
        }                                                                  \
    } while (0)

#define LOADB(KH, BB) do {                                                 \
        _Pragma("unroll")                                                  \
        for (int g = 0; g < 4; ++g) {                                      \
            int c_ = cb64 + g * 16 + lp;                                   \
            bf[g] = *(const Frag*)(lds + (BB) + boff + (c_ << 7)           \
                     + ((((((KH) << 2) | lg) ^ (c_ & 7))) << 4));          \
        }                                                                  \
    } while (0)

#define MFMA16(MH) do {                                                    \
        __builtin_amdgcn_s_setprio(1);                                     \
        _Pragma("unroll")                                                  \
        for (int f = 0; f < 4; ++f)                                        \
            _Pragma("unroll")                                              \
            for (int g = 0; g < 4; ++g)                                    \
                acc[(MH) * 4 + f][g] = __builtin_amdgcn_mfma_f32_16x16x32_f16( \
                    af[f].v, bf[g].v, acc[(MH) * 4 + f][g], 0, 0, 0);      \
        __builtin_amdgcn_s_setprio(0);                                     \
    } while (0)

    // prologue: stage tile 0 fully into buf 0 (8 loads/thread outstanding)
    STAGE(0, 0, 0); STAGE(0, 1, 0); STAGE(0, 2, 0); STAGE(0, 3, 0);

    for (int t = 0; t < 16; ++t) {
        int BB = (t & 1) << 16;
        int NB = BB ^ 65536;
        // ---- phase 0 (mh=0, kh=0): stage pair {h0,h1} of t+1, wait tile t
        STAGE(t + 1, 0, NB); STAGE(t + 1, 1, NB);
        asm volatile("s_waitcnt vmcnt(4)" ::: "memory");  // t landed; t+1's 4 fly
        __builtin_amdgcn_s_barrier();
        LOADB(0, BB); LOADA(0, 0, BB);
        MFMA16(0);
        __builtin_amdgcn_s_barrier();
        // ---- phase 1 (mh=1, kh=0): stage pair {h2,h3} of t+1
        LOADA(1, 0, BB);
        STAGE(t + 1, 2, NB); STAGE(t + 1, 3, NB);
        __builtin_amdgcn_s_barrier();
        MFMA16(1);
        __builtin_amdgcn_s_barrier();
        // ---- phase 2 (mh=0, kh=1): no staging
        LOADB(1, BB); LOADA(0, 1, BB);
        __builtin_amdgcn_s_barrier();
        MFMA16(0);
        __builtin_amdgcn_s_barrier();
        // ---- phase 3 (mh=1, kh=1): no staging
        LOADA(1, 1, BB);
        __builtin_amdgcn_s_barrier();
        MFMA16(1);
        __builtin_amdgcn_s_barrier();
    }
    // ---- tail: tile 16 (in buf 0), nothing left to stage
    {
        const int BB = 0;
        asm volatile("s_waitcnt vmcnt(0)" ::: "memory");
        __builtin_amdgcn_s_barrier();
        LOADB(0, BB); LOADA(0, 0, BB); MFMA16(0);
        __builtin_amdgcn_s_barrier();
        LOADA(1, 0, BB); MFMA16(1);
        __builtin_amdgcn_s_barrier();
        LOADB(1, BB); LOADA(0, 1, BB); MFMA16(0);
        __builtin_amdgcn_s_barrier();
        LOADA(1, 1, BB); MFMA16(1);
    }

    // epilogue: C[row = m0+wm+i*16+lg*4+r][col = n0+wn+j*16+lp]
    #pragma unroll
    for (int i = 0; i < 8; ++i)
        #pragma unroll
        for (int j = 0; j < 4; ++j) {
            int row = m0 + wm + i * 16 + (lg << 2);
            int col = n0 + wn + j * 16 + lp;
            float* p = out + (size_t)row * 1024 + col;
            #pragma unroll
            for (int r = 0; r < 4; ++r) p[(size_t)r * 1024] = acc[i][j][r];
        }
#undef STAGE
#undef LOADA
#undef LOADB
#undef MFMA16
}

// ============ host ============
extern "C" void kernel_launch(void* const* d_in, const int* in_sizes, int n_in,
                              void* d_out, int out_size, void* d_ws, size_t ws_size,
                              hipStream_t stream) {
    const float* S   = (const float*)d_in[0];
    const float* wsp = (const float*)d_in[1];
    const float* whp = (const float*)d_in[2];
    const float* whs = (const float*)d_in[3];
    const float* wtg = (const float*)d_in[4];
    const float* Wr  = (const float*)d_in[5];
    // d_in[6] = cache: fully overwritten by latent -> dead input
    const float* lat = (const float*)d_in[7];
    const float* Wk  = (const float*)d_in[8];
    const float* Wv  = (const float*)d_in[9];
    float* out = (float*)d_out;
    char*  ws  = (char*)d_ws;

    float* outk = out + 33554432ull;
    float* outv = out + 67108864ull;

    static bool lds_init = false;
    if (!lds_init) {
        hipFuncSetAttribute(reinterpret_cast<const void*>(gemm_read),
                            hipFuncAttributeMaxDynamicSharedMemorySize, 131072);
        lds_init = true;
    }

    const size_t A16_WS_OFF = (size_t)WS2_OFF + WS2_SZ;   // 2,752,512
    const size_t ws_need = A16_WS_OFF + A16_SZ;           // ~74 MB

    // dispatch 1: ws2 (Wk|Wv) prep only — kv blocks in dispatch 2 read it
    hipLaunchKernelGGL(prep_w, dim3(256), dim3(256), 0, stream, Wk, Wv, ws);

    if (ws_size >= ws_need) {
        // a16 in workspace: fuse || FULL kv (+W1-prep tail), then gemm_read
        char* a16 = ws + A16_WS_OFF;
        int nmain = 2048 * 19;
        hipLaunchKernelGGL(fuse_kv, dim3(nmain + 1088), dim3(256), 0, stream,
                           S, wsp, whp, whs, wtg, a16,
                           lat, ws + WS2_OFF, outk, outv, Wr, ws, 2, 19, nmain);
        hipLaunchKernelGGL(gemm_read, dim3(512), dim3(512), 131072, stream,
                           a16, ws, out);
    } else {
        // a16 aliases outv: fuse || k-half (+W1-prep tail); v after gemm_read
        char* a16 = (char*)outv;
        int nmain = 2048 * 18;
        hipLaunchKernelGGL(fuse_kv, dim3(nmain + 1088), dim3(256), 0, stream,
                           S, wsp, whp, whs, wtg, a16,
                           lat, ws + WS2_OFF, outk, outv, Wr, ws, 1, 18, nmain);
        hipLaunchKernelGGL(gemm_read, dim3(512), dim3(512), 131072, stream,
                           a16, ws, out);
        hipLaunchKernelGGL(gemm_v, dim3(2048), dim3(256), 0, stream,
                           lat, ws + WS2_OFF, outk, outv);
    }
}